// Round 1
// baseline (83.880 us; speedup 1.0000x reference)
//
#include <hip/hip_runtime.h>
#include <hip/hip_bf16.h>

// Problem: B=32, D=2048, NB=16, BS=512 (fp32 I/O)
//   out[b,r] = g[b, r>>7] * dot(W[r,:], x[b,:]) + bias[r]
//   g = sigmoid(x @ gate_w + gate_b); zero the 8 smallest gates per sample.
//
// Round-N structure: 2 kernels (was 3).
//   K1 (32 blocks):  UNCHANGED — gates[32][16] fp32 (exact top-8) + X -> bf16 Xbf
//   K2 (128 blocks, 512 thr): split-K moved from BLOCKS to WAVES.
//     8 waves/block each own a K=256 slice of the same 16 output rows x 32 batches
//     (per-wave inner loop identical to previous main_gemm wave), partials reduced
//     through LDS, gate+bias epilogue fused -> out. Kills K3 + 2MB partial buffer
//     round-trip + one launch gap. Same MFMA ops in the same accumulation order
//     as the verified 83us version -> bitwise-equivalent output path.

#define D_DIM 2048
#define B_DIM 32
#define NB_DIM 16
#define NWAVE 8                    // waves per K2 block = K-slices
#define KCHUNK (D_DIM / NWAVE)     // 256
#define PM_PAD 20                  // padded row stride (floats) for LDS partials

typedef __attribute__((ext_vector_type(4))) float f32x4;
typedef __attribute__((ext_vector_type(8))) float f32x8;
typedef __attribute__((ext_vector_type(8))) __bf16 bf16x8;

static __device__ __forceinline__ __bf16 f2bf(float f) {
    unsigned u = __builtin_bit_cast(unsigned, f);
    u += 0x7fffu + ((u >> 16) & 1u);           // round-to-nearest-even
    unsigned short h = (unsigned short)(u >> 16);
    return __builtin_bit_cast(__bf16, h);
}

static __device__ __forceinline__ bf16x8 load_cvt8(const float* p) {
    const f32x8 v = *(const f32x8*)p;          // 32B: two dwordx4
    bf16x8 r;
#pragma unroll
    for (int i = 0; i < 8; ++i) r[i] = f2bf(v[i]);
    return r;
}

// ---------------- Kernel 1: gates (fp32, exact) + X->bf16 ----------------
__global__ __launch_bounds__(256) void prep_kernel(
    const float* __restrict__ X,    // [32][2048]
    const float* __restrict__ GW,   // [2048][16]
    const float* __restrict__ GB,   // [16]
    float* __restrict__ gates,      // ws: [32][16]
    __bf16* __restrict__ Xbf)       // ws: [32][2048]
{
    __shared__ float red[NB_DIM][256];
    __shared__ float sg[NB_DIM];
    const int b = blockIdx.x;
    const int t = threadIdx.x;

    {   // convert this sample's X row to bf16 (32B loads / 16B stores)
        const int idx = b * D_DIM + t * 8;
        *(bf16x8*)(Xbf + idx) = load_cvt8(X + idx);
    }

    float acc[NB_DIM];
#pragma unroll
    for (int n = 0; n < NB_DIM; ++n) acc[n] = 0.f;

#pragma unroll
    for (int i = 0; i < D_DIM / 256; ++i) {
        const int c = t + i * 256;
        const float xv = X[b * D_DIM + c];
        const float* gw = GW + c * NB_DIM;
#pragma unroll
        for (int n = 0; n < NB_DIM; ++n) acc[n] += xv * gw[n];
    }
#pragma unroll
    for (int n = 0; n < NB_DIM; ++n) red[n][t] = acc[n];
    __syncthreads();
    for (int s = 128; s > 0; s >>= 1) {
        if (t < s) {
#pragma unroll
            for (int n = 0; n < NB_DIM; ++n) red[n][t] += red[n][t + s];
        }
        __syncthreads();
    }
    if (t < NB_DIM) {
        const float v = red[t][0] + GB[t];
        sg[t] = 1.f / (1.f + __expf(-v));
    }
    __syncthreads();
    if (t < NB_DIM) {
        const float g = sg[t];
        int rank = 0;  // gates smaller (ties: lower index smaller, matches lax.top_k drop)
#pragma unroll
        for (int m = 0; m < NB_DIM; ++m) {
            const float gm = sg[m];
            if (gm < g || (gm == g && m < t)) rank++;
        }
        gates[b * NB_DIM + t] = (rank >= NB_DIM / 2) ? g : 0.f;
    }
}

// ---------------- Kernel 2: fused GEMM (split-K across waves) + reduce + epilogue ----
// 128 blocks x 512 threads. Block rt owns rows r0=rt*16 (all 32 batches, full K).
// Wave w computes the K-slice [w*256, w*256+256) partial for all 16 rows x 32 batches
// (identical inner loop to previous main_gemm wave), dumps it to LDS, then all 512
// threads reduce 8 partials, apply gate+bias, and write out. No global partials, no K3.
__global__ __launch_bounds__(512) void main_fused(
    const float* __restrict__ W,      // [2048][2048]
    const __bf16* __restrict__ Xbf,   // ws: [32][2048]
    const float* __restrict__ gates,  // ws: [32][16]
    const float* __restrict__ bias,   // [2048]
    float* __restrict__ out)          // [32][2048]
{
    __shared__ float pm[NWAVE * B_DIM * PM_PAD];   // [wave][batch][row(+pad)] = 20 KB

    const int rt   = blockIdx.x;          // 0..127 row-tile
    const int wave = threadIdx.x >> 6;    // 0..7 = K-slice
    const int lane = threadIdx.x & 63;
    const int l15  = lane & 15;
    const int q    = lane >> 4;

    const int r0 = rt * 16;
    const int k0 = wave * KCHUNK;

    const float*  arow = W   + (size_t)(r0 + l15) * D_DIM + k0 + q * 8;
    const __bf16* b0p  = Xbf + (size_t)(l15)      * D_DIM + k0 + q * 8;
    const __bf16* b1p  = Xbf + (size_t)(l15 + 16) * D_DIM + k0 + q * 8;

    f32x4 acc0 = {0.f, 0.f, 0.f, 0.f};
    f32x4 acc1 = {0.f, 0.f, 0.f, 0.f};

#pragma unroll
    for (int kk = 0; kk < KCHUNK / 32; ++kk) {   // 8 MFMA k-steps per wave
        const bf16x8 av  = load_cvt8(arow + kk * 32);            // W fp32 -> bf16
        const bf16x8 bv0 = *(const bf16x8*)(b0p + kk * 32);      // Xbf direct 16B
        const bf16x8 bv1 = *(const bf16x8*)(b1p + kk * 32);
        acc0 = __builtin_amdgcn_mfma_f32_16x16x32_bf16(av, bv0, acc0, 0, 0, 0);
        acc1 = __builtin_amdgcn_mfma_f32_16x16x32_bf16(av, bv1, acc1, 0, 0, 0);
    }

    // C/D: col(batch) = lane&15, row(W-row offset) = (lane>>4)*4 + reg
    float* base = pm + wave * (B_DIM * PM_PAD);
    *(f32x4*)(base + l15 * PM_PAD + q * 4)        = acc0;   // batches 0..15
    *(f32x4*)(base + (l15 + 16) * PM_PAD + q * 4) = acc1;   // batches 16..31
    __syncthreads();

    // 512 threads reduce 512 outputs: t -> (batch lb, row)
    const int t   = threadIdx.x;
    const int lb  = t >> 4;          // 0..31
    const int row = t & 15;          // 0..15
    float s = 0.f;
#pragma unroll
    for (int w = 0; w < NWAVE; ++w)
        s += pm[w * (B_DIM * PM_PAD) + lb * PM_PAD + row];

    const float g  = gates[lb * NB_DIM + (r0 >> 7)];
    const float bi = bias[r0 + row];
    out[(size_t)lb * D_DIM + r0 + row] = g * s + bi;
}

extern "C" void kernel_launch(void* const* d_in, const int* in_sizes, int n_in,
                              void* d_out, int out_size, void* d_ws, size_t ws_size,
                              hipStream_t stream) {
    const float* x    = (const float*)d_in[0];  // [32][2048]
    const float* gw   = (const float*)d_in[1];  // [2048][16]
    const float* gb   = (const float*)d_in[2];  // [16]
    const float* w    = (const float*)d_in[3];  // [2048][2048]
    const float* bias = (const float*)d_in[4];  // [2048]
    float* out = (float*)d_out;

    float*  gates = (float*)d_ws;                        // 2 KB
    __bf16* Xbf   = (__bf16*)((char*)d_ws + 4096);       // 128 KB

    prep_kernel<<<B_DIM, 256, 0, stream>>>(x, gw, gb, gates, Xbf);
    main_fused<<<D_DIM / 16, 512, 0, stream>>>(w, Xbf, gates, bias, out);
}

// Round 2
// 83.047 us; speedup vs baseline: 1.0100x; 1.0100x over previous
//
#include <hip/hip_runtime.h>
#include <hip/hip_bf16.h>

// Problem: B=32, D=2048, NB=16, BS=512 (fp32 I/O)
//   out[b,r] = g[b, r>>7] * dot(W[r,:], x[b,:]) + bias[r]
//   g = sigmoid(x @ gate_w + gate_b); zero the 8 smallest gates per sample.
//
// Round-2 structure: timed region = harness 256MB poison fill (~43us, fixed) + us.
//   K1 gate_part (256 blocks, full GPU): fp32 gate-logit PARTIALS [32][8][16] -> ws.
//     Coalesced 64B GW row loads, proven LDS-tree reduce. No Xbf (deleted).
//   K2 mega (256 blocks = 128 row-tiles x 2 batch-halves, 512 thr):
//     MFMA with BOTH operands cvt'd fp32->bf16 in flight (f2bf identical to old
//     staged path -> same numerics). 8 waves split K=2048 into 256-slices (same
//     accumulation order as verified round-1). LDS partial reduce + gate finalize
//     (sum 8 partials + GB, sigmoid, exact top-8 rank) + bias -> out.

#define D_DIM 2048
#define B_DIM 32
#define NB_DIM 16
#define NWAVE 8                    // K-slices per mega block
#define KCHUNK (D_DIM / NWAVE)     // 256

typedef __attribute__((ext_vector_type(4))) float f32x4;
typedef __attribute__((ext_vector_type(8))) float f32x8;
typedef __attribute__((ext_vector_type(8))) __bf16 bf16x8;

static __device__ __forceinline__ __bf16 f2bf(float f) {
    unsigned u = __builtin_bit_cast(unsigned, f);
    u += 0x7fffu + ((u >> 16) & 1u);           // round-to-nearest-even
    unsigned short h = (unsigned short)(u >> 16);
    return __builtin_bit_cast(__bf16, h);
}

static __device__ __forceinline__ bf16x8 load_cvt8(const float* p) {
    const f32x8 v = *(const f32x8*)p;          // 32B: two dwordx4
    bf16x8 r;
#pragma unroll
    for (int i = 0; i < 8; ++i) r[i] = f2bf(v[i]);
    return r;
}

// ---------------- Kernel 1: gate-logit partials (fp32, exact) ----------------
// 256 blocks = 32 batches x 8 K-slices, 256 threads. Thread t owns one column
// c = ks*256+t: 16 products, then LDS tree (same shape as the verified prep).
__global__ __launch_bounds__(256) void gate_part(
    const float* __restrict__ X,    // [32][2048]
    const float* __restrict__ GW,   // [2048][16]
    float* __restrict__ gp)         // ws: [32][8][16] logit partials
{
    __shared__ float red[NB_DIM][256];
    const int b  = blockIdx.x >> 3;
    const int ks = blockIdx.x & 7;
    const int t  = threadIdx.x;
    const int c  = ks * 256 + t;

    const float xv = X[b * D_DIM + c];
    const f32x4 g0 = *(const f32x4*)(GW + c * NB_DIM + 0);   // 64B row, coalesced
    const f32x4 g1 = *(const f32x4*)(GW + c * NB_DIM + 4);
    const f32x4 g2 = *(const f32x4*)(GW + c * NB_DIM + 8);
    const f32x4 g3 = *(const f32x4*)(GW + c * NB_DIM + 12);

#pragma unroll
    for (int n = 0; n < 4; ++n) red[n][t]      = xv * g0[n];
#pragma unroll
    for (int n = 0; n < 4; ++n) red[n + 4][t]  = xv * g1[n];
#pragma unroll
    for (int n = 0; n < 4; ++n) red[n + 8][t]  = xv * g2[n];
#pragma unroll
    for (int n = 0; n < 4; ++n) red[n + 12][t] = xv * g3[n];
    __syncthreads();

    for (int s = 128; s > 0; s >>= 1) {
        if (t < s) {
#pragma unroll
            for (int n = 0; n < NB_DIM; ++n) red[n][t] += red[n][t + s];
        }
        __syncthreads();
    }
    if (t < NB_DIM) gp[b * (8 * NB_DIM) + ks * NB_DIM + t] = red[t][0];
}

// ---------------- Kernel 2: MFMA + reduce + gate finalize + epilogue ----------
// 256 blocks x 512 threads. bid: rt = bid&127 (16 W-rows), bh = bid>>7 (16
// batches). bid and bid+128 share W rows and land on the same XCD (bid%8 equal)
// -> W fetched ~once per L2. Wave w = K-slice [w*256, w*256+256).
__global__ __launch_bounds__(512) void mega(
    const float* __restrict__ W,      // [2048][2048]
    const float* __restrict__ X,      // [32][2048]
    const float* __restrict__ gp,     // ws: [32][8][16]
    const float* __restrict__ GB,     // [16]
    const float* __restrict__ bias,   // [2048]
    float* __restrict__ out)          // [32][2048]
{
    __shared__ float pm[NWAVE][16][20];   // [wave][batch][row(+pad)] = 10 KB
    __shared__ float sg[16];              // masked gate per local batch

    const int bid  = blockIdx.x;
    const int rt   = bid & 127;
    const int bh   = bid >> 7;
    const int wave = threadIdx.x >> 6;
    const int lane = threadIdx.x & 63;
    const int l15  = lane & 15;
    const int q    = lane >> 4;

    const int r0 = rt * 16;
    const int k0 = wave * KCHUNK;

    const float* arow = W + (size_t)(r0 + l15) * D_DIM + k0 + q * 8;
    const float* xrow = X + (size_t)(bh * 16 + l15) * D_DIM + k0 + q * 8;

    f32x4 acc = {0.f, 0.f, 0.f, 0.f};
#pragma unroll
    for (int kk = 0; kk < KCHUNK / 32; ++kk) {   // 8 MFMA k-steps per wave
        const bf16x8 av = load_cvt8(arow + kk * 32);   // W fp32 -> bf16
        const bf16x8 bv = load_cvt8(xrow + kk * 32);   // X fp32 -> bf16 (== old Xbf)
        acc = __builtin_amdgcn_mfma_f32_16x16x32_bf16(av, bv, acc, 0, 0, 0);
    }
    // C/D: col(batch) = lane&15, row(W-row offset) = (lane>>4)*4 + reg
    *(f32x4*)&pm[wave][l15][q * 4] = acc;

    // gate finalize: 16 lanes of wave 0 (overlaps other waves' MFMA tails)
    if (threadIdx.x < NB_DIM) {
        const int b = bh * 16 + threadIdx.x;
        const float* p = gp + b * (8 * NB_DIM);
        float lg[NB_DIM];
#pragma unroll
        for (int n = 0; n < NB_DIM; ++n) lg[n] = GB[n];
#pragma unroll
        for (int ks = 0; ks < 8; ++ks)
#pragma unroll
            for (int n = 0; n < NB_DIM; ++n) lg[n] += p[ks * NB_DIM + n];
        float g[NB_DIM];
#pragma unroll
        for (int n = 0; n < NB_DIM; ++n) g[n] = 1.f / (1.f + __expf(-lg[n]));
        const int nb = rt >> 3;                 // gate block for rows r0..r0+15
        float gn = 0.f;                         // g[nb] via static select (no scratch)
#pragma unroll
        for (int n = 0; n < NB_DIM; ++n) gn = (n == nb) ? g[n] : gn;
        int rank = 0;  // ties: lower index smaller (matches lax.top_k drop)
#pragma unroll
        for (int m = 0; m < NB_DIM; ++m)
            if (g[m] < gn || (g[m] == gn && m < nb)) rank++;
        sg[threadIdx.x] = (rank >= NB_DIM / 2) ? gn : 0.f;
    }
    __syncthreads();

    // epilogue: 64 lanes, f32x4 each: 256 outputs
    if (threadIdx.x < 64) {
        const int lb = threadIdx.x >> 2;          // local batch 0..15
        const int r4 = (threadIdx.x & 3) * 4;     // row quad 0,4,8,12
        f32x4 s = {0.f, 0.f, 0.f, 0.f};
#pragma unroll
        for (int w = 0; w < NWAVE; ++w)
            s += *(const f32x4*)&pm[w][lb][r4];
        const float gv = sg[lb];
        const f32x4 bi = *(const f32x4*)(bias + r0 + r4);
        f32x4 y;
#pragma unroll
        for (int i = 0; i < 4; ++i) y[i] = gv * s[i] + bi[i];
        *(f32x4*)(out + (size_t)(bh * 16 + lb) * D_DIM + r0 + r4) = y;
    }
}

extern "C" void kernel_launch(void* const* d_in, const int* in_sizes, int n_in,
                              void* d_out, int out_size, void* d_ws, size_t ws_size,
                              hipStream_t stream) {
    const float* x    = (const float*)d_in[0];  // [32][2048]
    const float* gw   = (const float*)d_in[1];  // [2048][16]
    const float* gb   = (const float*)d_in[2];  // [16]
    const float* w    = (const float*)d_in[3];  // [2048][2048]
    const float* bias = (const float*)d_in[4];  // [2048]
    float* out = (float*)d_out;

    float* gp = (float*)d_ws;                   // 32*8*16 fp32 = 16 KB

    gate_part<<<B_DIM * 8, 256, 0, stream>>>(x, gw, gp);
    mega<<<256, 512, 0, stream>>>(w, x, gp, gb, bias, out);
}

// Round 4
// 80.945 us; speedup vs baseline: 1.0363x; 1.0260x over previous
//
#include <hip/hip_runtime.h>
#include <hip/hip_bf16.h>

// Problem: B=32, D=2048, NB=16, BS=512 (fp32 I/O)
//   out[b,r] = g[b, r>>7] * dot(W[r,:], x[b,:]) + bias[r]
//   g = sigmoid(x @ gate_w + gate_b); zero the 8 smallest gates per sample.
//
// Round-4 = round-3 resubmitted verbatim (round-3 bench died on GPU acquisition
// timeout; the falsification test never ran).
// SINGLE kernel (falsification test for the fixed-floor hypothesis:
// rounds 0-2 measured 83.1/83.9/83.0 for wildly different pipelines).
//   mega (256 blocks = 128 row-tiles x 2 batch-halves, 512 thr):
//     - main path: W fp32->bf16 (RNE) x X fp32->bf16 (RNE) MFMA, 8 waves split
//       K=2048 into 256-slices — IDENTICAL fragments/accumulation order to the
//       verified round-2 kernel.
//     - gates fused: A=GW^T fragment, B = the SAME X fragment, hi/lo bf16 split
//       on both operands (3 MFMAs) -> logit error ~1e-5 (rank-flip safe, vs
//       bf16-single ~4e-3 which risks the top-8 cliff). Reduce in LDS, add GB,
//       sigmoid, exact rank-mask, then gate+bias epilogue -> out.
//   No workspace, no second launch, no inter-block dependency.

#define D_DIM 2048
#define B_DIM 32
#define NB_DIM 16
#define NWAVE 8                    // K-slices per block
#define KCHUNK (D_DIM / NWAVE)     // 256

typedef __attribute__((ext_vector_type(4))) float f32x4;
typedef __attribute__((ext_vector_type(8))) float f32x8;
typedef __attribute__((ext_vector_type(8))) __bf16 bf16x8;

static __device__ __forceinline__ __bf16 f2bf(float f) {
    unsigned u = __builtin_bit_cast(unsigned, f);
    u += 0x7fffu + ((u >> 16) & 1u);           // round-to-nearest-even
    unsigned short h = (unsigned short)(u >> 16);
    return __builtin_bit_cast(__bf16, h);
}

static __device__ __forceinline__ float bf2f(__bf16 h) {
    unsigned u = ((unsigned)__builtin_bit_cast(unsigned short, h)) << 16;
    return __builtin_bit_cast(float, u);
}

static __device__ __forceinline__ bf16x8 load_cvt8(const float* p) {
    const f32x8 v = *(const f32x8*)p;          // 32B: two dwordx4
    bf16x8 r;
#pragma unroll
    for (int i = 0; i < 8; ++i) r[i] = f2bf(v[i]);
    return r;
}

// ---------------- the one kernel ----------------
// bid: rt = bid&127 (16 W-rows), bh = bid>>7 (16 batches). bid and bid+128
// share W rows and land on the same XCD (bid%8 equal) -> W fetched ~once per L2.
// Wave w owns K-slice [w*256, w*256+256).
__global__ __launch_bounds__(512) void mega(
    const float* __restrict__ W,      // [2048][2048]
    const float* __restrict__ X,      // [32][2048]
    const float* __restrict__ GW,     // [2048][16]
    const float* __restrict__ GB,     // [16]
    const float* __restrict__ bias,   // [2048]
    float* __restrict__ out)          // [32][2048]
{
    __shared__ float pm [NWAVE][16][20];  // main partials [wave][batch][row+pad] 10 KB
    __shared__ float pmg[NWAVE][16][20];  // gate partials [wave][batch][n+pad]  10 KB
    __shared__ float sgm[16][17];         // sigmoid(logit) [batch][n]
    __shared__ float sg[16];              // masked gate per local batch

    const int bid  = blockIdx.x;
    const int rt   = bid & 127;
    const int bh   = bid >> 7;
    const int wave = threadIdx.x >> 6;
    const int lane = threadIdx.x & 63;
    const int l15  = lane & 15;
    const int q    = lane >> 4;

    const int r0 = rt * 16;
    const int k0 = wave * KCHUNK;

    const float* arow = W  + (size_t)(r0 + l15) * D_DIM + k0 + q * 8;
    const float* xrow = X  + (size_t)(bh * 16 + l15) * D_DIM + k0 + q * 8;
    // GW^T A-fragment: A[m=n_gate=l15][k=q*8+j] = GW[k0 + kk*32 + q*8 + j][l15]
    const float* gwp  = GW + (size_t)(k0 + q * 8) * NB_DIM + l15;

    f32x4 acc  = {0.f, 0.f, 0.f, 0.f};
    f32x4 gacc = {0.f, 0.f, 0.f, 0.f};

#pragma unroll
    for (int kk = 0; kk < KCHUNK / 32; ++kk) {   // 8 MFMA k-steps per wave
        const bf16x8 av = load_cvt8(arow + kk * 32);   // W fp32 -> bf16 (RNE)

        const f32x8 xv = *(const f32x8*)(xrow + kk * 32);
        bf16x8 bhi, blo;                               // X hi (== old path) + lo
#pragma unroll
        for (int i = 0; i < 8; ++i) {
            bhi[i] = f2bf(xv[i]);
            blo[i] = f2bf(xv[i] - bf2f(bhi[i]));
        }
        bf16x8 ghi, glo;                               // GW^T hi + lo
#pragma unroll
        for (int j = 0; j < 8; ++j) {
            const float gv = gwp[(kk * 32 + j) * NB_DIM];
            ghi[j] = f2bf(gv);
            glo[j] = f2bf(gv - bf2f(ghi[j]));
        }

        acc  = __builtin_amdgcn_mfma_f32_16x16x32_bf16(av,  bhi, acc,  0, 0, 0);
        gacc = __builtin_amdgcn_mfma_f32_16x16x32_bf16(ghi, bhi, gacc, 0, 0, 0);
        gacc = __builtin_amdgcn_mfma_f32_16x16x32_bf16(ghi, blo, gacc, 0, 0, 0);
        gacc = __builtin_amdgcn_mfma_f32_16x16x32_bf16(glo, bhi, gacc, 0, 0, 0);
    }

    // C/D: col = lane&15, row = (lane>>4)*4 + reg
    *(f32x4*)&pm [wave][l15][q * 4] = acc;    // [batch][W-row offset]
    *(f32x4*)&pmg[wave][l15][q * 4] = gacc;   // [batch][gate n]
    __syncthreads();

    // gate logits: sum 8 K-slice partials + GB, sigmoid
    if (threadIdx.x < 256) {
        const int lb = threadIdx.x >> 4;
        const int n  = threadIdx.x & 15;
        float s = GB[n];
#pragma unroll
        for (int w = 0; w < NWAVE; ++w) s += pmg[w][lb][n];
        sgm[lb][n] = 1.f / (1.f + __expf(-s));
    }
    __syncthreads();

    // exact top-8 mask (ties: lower index smaller, matches lax.top_k drop)
    if (threadIdx.x < 16) {
        const int lb = threadIdx.x;
        const int nb = rt >> 3;               // gate block for rows r0..r0+15
        const float gn = sgm[lb][nb];
        int rank = 0;
#pragma unroll
        for (int m = 0; m < NB_DIM; ++m) {
            const float gm = sgm[lb][m];
            if (gm < gn || (gm == gn && m < nb)) rank++;
        }
        sg[lb] = (rank >= NB_DIM / 2) ? gn : 0.f;
    }
    __syncthreads();

    // epilogue: 64 lanes, f32x4 each: 256 outputs
    if (threadIdx.x < 64) {
        const int lb = threadIdx.x >> 2;          // local batch 0..15
        const int r4 = (threadIdx.x & 3) * 4;     // row quad 0,4,8,12
        f32x4 s = {0.f, 0.f, 0.f, 0.f};
#pragma unroll
        for (int w = 0; w < NWAVE; ++w)
            s += *(const f32x4*)&pm[w][lb][r4];
        const float gv = sg[lb];
        const f32x4 bi = *(const f32x4*)(bias + r0 + r4);
        f32x4 y;
#pragma unroll
        for (int i = 0; i < 4; ++i) y[i] = gv * s[i] + bi[i];
        *(f32x4*)(out + (size_t)(bh * 16 + lb) * D_DIM + r0 + r4) = y;
    }
}

extern "C" void kernel_launch(void* const* d_in, const int* in_sizes, int n_in,
                              void* d_out, int out_size, void* d_ws, size_t ws_size,
                              hipStream_t stream) {
    const float* x    = (const float*)d_in[0];  // [32][2048]
    const float* gw   = (const float*)d_in[1];  // [2048][16]
    const float* gb   = (const float*)d_in[2];  // [16]
    const float* w    = (const float*)d_in[3];  // [2048][2048]
    const float* bias = (const float*)d_in[4];  // [2048]
    float* out = (float*)d_out;

    mega<<<256, 512, 0, stream>>>(w, x, gw, gb, bias, out);
}